// Round 4
// baseline (386.548 us; speedup 1.0000x reference)
//
#include <hip/hip_runtime.h>
#include <hip/hip_bf16.h>
#include <math.h>

#define B_N 64
#define C_N 512
#define M_N 1024

typedef __attribute__((ext_vector_type(8))) short bf16x8;
typedef __attribute__((ext_vector_type(4))) float f32x4;

__device__ __forceinline__ float b2f(unsigned short u) {
  unsigned int x = ((unsigned int)u) << 16;
  return __builtin_bit_cast(float, x);
}
__device__ __forceinline__ unsigned short f2b(float f) {
  unsigned int x = __builtin_bit_cast(unsigned int, f);
  unsigned int lsb = (x >> 16) & 1u;
  x += 0x7fffu + lsb;
  return (unsigned short)(x >> 16);
}
__device__ __forceinline__ float bround(float f) { return b2f(f2b(f)); }

typedef __attribute__((address_space(1))) const unsigned int gas_uint;
typedef __attribute__((address_space(3))) unsigned int las_uint;
__device__ __forceinline__ void async_ld(const void* g, const void* l) {
  __builtin_amdgcn_global_load_lds((gas_uint*)(uintptr_t)g,
                                   (las_uint*)(unsigned int)(uintptr_t)l, 16, 0, 0);
}

// ---------- dtype detection ----------
__global__ void k_detect(const unsigned short* __restrict__ p, int* __restrict__ flag) {
  unsigned short u = p[threadIdx.x];
  int e = (u >> 7) & 0xff;
  int pl = (u == 0) || (e >= 110 && e <= 134);
  int cnt = __syncthreads_count(pl);
  if (threadIdx.x == 0) *flag = (cnt >= 208) ? 1 : 0;  // 1 = bf16, 0 = fp32
}

__global__ void k_mode(const int* __restrict__ flag, int wsOK, int* __restrict__ mode) {
  if (threadIdx.x == 0) *mode = (*flag == 1 && wsOK) ? 1 : 0;
}

// ---------- positional embedding, bf16 [C][M] ----------
__global__ void k_pe(unsigned short* __restrict__ pe) {
  int idx = blockIdx.x * 256 + threadIdx.x;
  int c = idx >> 10, m = idx & 1023;
  float freq = expf((float)(c & ~1) * (-9.210340371976184f / 512.0f));
  float ang = (float)m * freq;
  float v = (c & 1) ? cosf(ang) : sinf(ang);
  pe[idx] = f2b(v);
}

// ---------- per-row sums of pe ----------
__global__ void k_pesum(const unsigned short* __restrict__ pe, float* __restrict__ pesum) {
  int lane = threadIdx.x & 63;
  int row = blockIdx.x * 4 + (threadIdx.x >> 6);
  float s = 0.f;
  const uint4* p = (const uint4*)(pe + (size_t)row * M_N);
  for (int j = 0; j < 2; j++) {
    union { uint4 v; unsigned short u[8]; } a; a.v = p[j * 64 + lane];
    for (int k = 0; k < 8; k++) s += b2f(a.u[k]);
  }
  for (int off = 32; off; off >>= 1) s += __shfl_down(s, off);
  if (lane == 0) pesum[row] = s;
}

// ---------- row sums of h; rx = rb + pesum[c] ----------
__global__ void k_sums(const void* __restrict__ hin, const int* __restrict__ flag,
                       const float* __restrict__ pesum, float* __restrict__ rx,
                       float* __restrict__ rb) {
  int lane = threadIdx.x & 63;
  int row = blockIdx.x * 4 + (threadIdx.x >> 6);
  int f = *flag;
  float s = 0.f;
  if (f) {
    const uint4* h = (const uint4*)((const unsigned short*)hin + (size_t)row * M_N);
    for (int j = 0; j < 2; j++) {
      union { uint4 v; unsigned short u[8]; } a; a.v = h[j * 64 + lane];
      for (int k = 0; k < 8; k++) s += b2f(a.u[k]);
    }
  } else {
    const float4* h = (const float4*)((const float*)hin + (size_t)row * M_N);
    for (int j = 0; j < 4; j++) {
      float4 v = h[j * 64 + lane];
      s += v.x + v.y + v.z + v.w;
    }
  }
  for (int off = 32; off; off >>= 1) s += __shfl_down(s, off);
  if (lane == 0) { rb[row] = s; rx[row] = s + pesum[row & (C_N - 1)]; }
}

// ---------- gate ----------
__global__ void k_gate(const void* __restrict__ wp, const void* __restrict__ bp,
                       const int* __restrict__ flag, const float* __restrict__ rx,
                       float* __restrict__ gate) {
  int idx = blockIdx.x * 256 + threadIdx.x;
  int b = idx >> 9, c = idx & (C_N - 1);
  int f = *flag;
  float acc = 0.f;
  for (int k = 0; k < 5; ++k) {
    int cc = c + k - 2;
    if (cc < 0 || cc >= C_N) continue;
    float y = rx[b * C_N + cc] * (1.0f / 1024.0f);
    float w;
    if (f) { y = bround(y); w = b2f(((const unsigned short*)wp)[c * 5 + k]); }
    else   { w = ((const float*)wp)[c * 5 + k]; }
    acc += y * w;
  }
  float bias = f ? b2f(((const unsigned short*)bp)[c]) : ((const float*)bp)[c];
  float s = f ? bround(bround(acc) + bias) : (acc + bias);
  float g = 1.0f / (1.0f + expf(-s));
  if (f) g = bround(g);
  gate[idx] = g;
}

// ---------- P = PE PE^T (bf16), one 128x128 tile per block, grid (4,4) ------
__global__ __launch_bounds__(256, 2)
void k_P(const unsigned short* __restrict__ pe, unsigned short* __restrict__ Pout) {
  __shared__ unsigned short tiles[2][128 * 32];
  int t = threadIdx.x, lane = t & 63, w = t >> 6;
  int cblk = blockIdx.y * 128, dblk = blockIdx.x * 128;
  int gcol = (lane & 3) ^ ((lane >> 3) & 3);
  const unsigned short* srcp = pe
      + (size_t)((w ? dblk : cblk) + (lane >> 2)) * M_N + gcol * 8;
  int wr = (w >> 1) * 64, wc = (w & 1) * 64;
  int fr = lane & 15, kc = lane >> 4;
  int fcol = ((kc ^ ((fr >> 1) & 3))) * 8;

  f32x4 acc[4][4];
  const f32x4 z = {0.f, 0.f, 0.f, 0.f};
  for (int i = 0; i < 4; i++) for (int j = 0; j < 4; j++) acc[i][j] = z;

  for (int kk = 0; kk < M_N; kk += 32) {
    if (w < 2)
      for (int g = 0; g < 8; g++)
        async_ld(srcp + kk + (size_t)g * (16 * M_N), &tiles[w][g * 512]);
    __syncthreads();
    bf16x8 bf[4];
    for (int j = 0; j < 4; j++)
      bf[j] = *(const bf16x8*)&tiles[1][(wc + j * 16 + fr) * 32 + fcol];
    for (int i = 0; i < 4; i++) {
      bf16x8 af = *(const bf16x8*)&tiles[0][(wr + i * 16 + fr) * 32 + fcol];
      for (int j = 0; j < 4; j++)
        acc[i][j] = __builtin_amdgcn_mfma_f32_16x16x32_bf16(af, bf[j], acc[i][j], 0, 0, 0);
    }
    __syncthreads();
  }
  for (int i = 0; i < 4; i++)
    for (int r = 0; r < 4; r++) {
      int c = cblk + wr + i * 16 + kc * 4 + r;
      for (int j = 0; j < 4; j++) {
        int d = dblk + wc + j * 16 + fr;
        Pout[c * C_N + d] = f2b(acc[i][j][r]);
      }
    }
}

// ---------- FAST cov: S2=HH^T and U=(H PE^T + PE H^T) via async staging -----
// S1 = S2 + U + P;  cov = g_c g_d (S1/M - rx rx/M^2) + S2/M - rb rb/M^2.
// LDS [128][32] bf16 unpadded, XOR swizzle (chunk kc at pcol = kc ^ ((row>>1)&3)).
__global__ __launch_bounds__(256, 2)
void k_cov3(const unsigned short* __restrict__ h, const unsigned short* __restrict__ pe,
            const unsigned short* __restrict__ P, const int* __restrict__ mode,
            const float* __restrict__ rx, const float* __restrict__ rb,
            const float* __restrict__ gate, unsigned short* __restrict__ out,
            int b0, int swz) {
  if (*mode != 1) return;
  __shared__ unsigned short tiles[4][128 * 32];  // Ha, Pa, Hb, Pb = 32 KB
  int t = threadIdx.x, lane = t & 63, w = t >> 6;
  int bx, by, b;
  if (swz) {  // 16 blocks of one batch share an XCD slot (lid&7)
    int lid = blockIdx.x;
    b = b0 + (lid >> 7) * 8 + (lid & 7);
    int s = (lid >> 3) & 15; bx = s & 3; by = s >> 2;
  } else { bx = blockIdx.x; by = blockIdx.y; b = b0 + blockIdx.z; }
  int cblk = by * 128, dblk = bx * 128;

  // wave w stages tile w: 0=H rows cblk, 1=PE rows cblk, 2=H rows dblk, 3=PE rows dblk
  int rowbase = (w & 2) ? dblk : cblk;
  int gcol = (lane & 3) ^ ((lane >> 3) & 3);
  const unsigned short* srcp;
  if (w & 1) srcp = pe + (size_t)(rowbase + (lane >> 2)) * M_N + gcol * 8;
  else       srcp = h + (size_t)b * (C_N * M_N)
                      + (size_t)(rowbase + (lane >> 2)) * M_N + gcol * 8;

  int wr = (w >> 1) * 64, wc = (w & 1) * 64;
  int fr = lane & 15, kc = lane >> 4;
  int fcol = ((kc ^ ((fr >> 1) & 3))) * 8;

  f32x4 aS[4][4], aU[4][4];
  const f32x4 z = {0.f, 0.f, 0.f, 0.f};
  for (int i = 0; i < 4; i++)
    for (int j = 0; j < 4; j++) { aS[i][j] = z; aU[i][j] = z; }

  for (int kk = 0; kk < M_N; kk += 32) {
    for (int g = 0; g < 8; g++)
      async_ld(srcp + kk + (size_t)g * (16 * M_N), &tiles[w][g * 512]);
    __syncthreads();

    bf16x8 bH[4], bP[4];
    for (int j = 0; j < 4; j++) {
      int off = (wc + j * 16 + fr) * 32 + fcol;
      bH[j] = *(const bf16x8*)&tiles[2][off];
      bP[j] = *(const bf16x8*)&tiles[3][off];
    }
    for (int i = 0; i < 4; i++) {
      int off = (wr + i * 16 + fr) * 32 + fcol;
      bf16x8 aH = *(const bf16x8*)&tiles[0][off];
      bf16x8 aP = *(const bf16x8*)&tiles[1][off];
      for (int j = 0; j < 4; j++) {
        aS[i][j] = __builtin_amdgcn_mfma_f32_16x16x32_bf16(aH, bH[j], aS[i][j], 0, 0, 0);
        aU[i][j] = __builtin_amdgcn_mfma_f32_16x16x32_bf16(aH, bP[j], aU[i][j], 0, 0, 0);
        aU[i][j] = __builtin_amdgcn_mfma_f32_16x16x32_bf16(aP, bH[j], aU[i][j], 0, 0, 0);
      }
    }
    __syncthreads();
  }

  const float invM = 1.0f / 1024.0f, invM2 = invM * invM;
  const float* gb = gate + b * C_N;
  const float* rxb = rx + b * C_N;
  const float* rbb = rb + b * C_N;
  for (int i = 0; i < 4; i++)
    for (int r = 0; r < 4; r++) {
      int c = cblk + wr + i * 16 + kc * 4 + r;
      float gc = gb[c], rxc = rxb[c], rbc = rbb[c];
      for (int j = 0; j < 4; j++) {
        int d = dblk + wc + j * 16 + fr;
        float S2 = aS[i][j][r];
        float S1 = S2 + aU[i][j][r] + b2f(P[c * C_N + d]);
        float v = gc * gb[d] * (S1 * invM - rxc * rxb[d] * invM2)
                + (S2 * invM - rbc * rbb[d] * invM2);
        if (c == d) v += 1e-8f;
        out[((size_t)b * C_N + c) * C_N + d] = f2b(v);
      }
    }
}

// ---------- SLOW cov (fallback: fp32 input or tiny ws) ----------
__global__ __launch_bounds__(256, 2)
void k_cov(const void* __restrict__ hin, const unsigned short* __restrict__ pe,
           const int* __restrict__ flag, const int* __restrict__ mode,
           const float* __restrict__ rx, const float* __restrict__ rb,
           const float* __restrict__ gate, void* __restrict__ out) {
  if (*mode != 0) return;
  __shared__ unsigned short sXa[128 * 40];
  __shared__ unsigned short sHa[128 * 40];
  __shared__ unsigned short sXb[128 * 40];
  __shared__ unsigned short sHb[128 * 40];

  int t = threadIdx.x;
  int b = blockIdx.z;
  int cblk = blockIdx.y * 128, dblk = blockIdx.x * 128;
  int f = *flag;
  int lane = t & 63, wave = t >> 6;
  int wr = (wave >> 1) * 64, wc = (wave & 1) * 64;
  int fr = lane & 15, fk = (lane >> 4) * 8;
  int sr = t >> 1, sc = (t & 1) * 16;

  f32x4 acc1[4][4], acc2[4][4];
  const f32x4 z = {0.f, 0.f, 0.f, 0.f};
  for (int i = 0; i < 4; i++)
    for (int j = 0; j < 4; j++) { acc1[i][j] = z; acc2[i][j] = z; }

  const size_t hb0 = (size_t)b * C_N * M_N;
  const unsigned short* peA = pe + (size_t)(cblk + sr) * M_N + sc;
  const unsigned short* peB = pe + (size_t)(dblk + sr) * M_N + sc;
  const unsigned short* hA16 = (const unsigned short*)hin + hb0 + (size_t)(cblk + sr) * M_N + sc;
  const unsigned short* hB16 = (const unsigned short*)hin + hb0 + (size_t)(dblk + sr) * M_N + sc;
  const float* hA32 = (const float*)hin + hb0 + (size_t)(cblk + sr) * M_N + sc;
  const float* hB32 = (const float*)hin + hb0 + (size_t)(dblk + sr) * M_N + sc;

  union U { uint4 v[2]; unsigned short u[16]; };

  for (int kk = 0; kk < M_N; kk += 32) {
    U pa, pb, wxa, wha, wxb, whb;
    {
      const uint4* ppa = reinterpret_cast<const uint4*>(peA + kk);
      pa.v[0] = ppa[0]; pa.v[1] = ppa[1];
      const uint4* ppb = reinterpret_cast<const uint4*>(peB + kk);
      pb.v[0] = ppb[0]; pb.v[1] = ppb[1];
    }
    if (f) {
      U ua, ub;
      const uint4* qa = reinterpret_cast<const uint4*>(hA16 + kk);
      ua.v[0] = qa[0]; ua.v[1] = qa[1];
      const uint4* qb = reinterpret_cast<const uint4*>(hB16 + kk);
      ub.v[0] = qb[0]; ub.v[1] = qb[1];
      for (int e = 0; e < 16; e++) {
        wha.u[e] = ua.u[e];
        whb.u[e] = ub.u[e];
        wxa.u[e] = f2b(b2f(ua.u[e]) + b2f(pa.u[e]));
        wxb.u[e] = f2b(b2f(ub.u[e]) + b2f(pb.u[e]));
      }
    } else {
      float fa[16], fb[16];
      const float4* qa = reinterpret_cast<const float4*>(hA32 + kk);
      const float4* qb = reinterpret_cast<const float4*>(hB32 + kk);
      for (int e = 0; e < 4; e++) {
        float4 va = qa[e], vb = qb[e];
        fa[4 * e + 0] = va.x; fa[4 * e + 1] = va.y; fa[4 * e + 2] = va.z; fa[4 * e + 3] = va.w;
        fb[4 * e + 0] = vb.x; fb[4 * e + 1] = vb.y; fb[4 * e + 2] = vb.z; fb[4 * e + 3] = vb.w;
      }
      for (int e = 0; e < 16; e++) {
        wha.u[e] = f2b(fa[e]);
        whb.u[e] = f2b(fb[e]);
        wxa.u[e] = f2b(fa[e] + b2f(pa.u[e]));
        wxb.u[e] = f2b(fb[e] + b2f(pb.u[e]));
      }
    }
    {
      uint4* d0 = reinterpret_cast<uint4*>(&sXa[sr * 40 + sc]);
      d0[0] = wxa.v[0]; d0[1] = wxa.v[1];
      uint4* d1 = reinterpret_cast<uint4*>(&sHa[sr * 40 + sc]);
      d1[0] = wha.v[0]; d1[1] = wha.v[1];
      uint4* d2 = reinterpret_cast<uint4*>(&sXb[sr * 40 + sc]);
      d2[0] = wxb.v[0]; d2[1] = wxb.v[1];
      uint4* d3 = reinterpret_cast<uint4*>(&sHb[sr * 40 + sc]);
      d3[0] = whb.v[0]; d3[1] = whb.v[1];
    }
    __syncthreads();

    bf16x8 bX[4], bH[4];
    for (int j = 0; j < 4; j++) {
      int dr = wc + j * 16 + fr;
      bX[j] = *reinterpret_cast<const bf16x8*>(&sXb[dr * 40 + fk]);
      bH[j] = *reinterpret_cast<const bf16x8*>(&sHb[dr * 40 + fk]);
    }
    for (int i = 0; i < 4; i++) {
      int cr = wr + i * 16 + fr;
      bf16x8 aX = *reinterpret_cast<const bf16x8*>(&sXa[cr * 40 + fk]);
      bf16x8 aH = *reinterpret_cast<const bf16x8*>(&sHa[cr * 40 + fk]);
      for (int j = 0; j < 4; j++) {
        acc1[i][j] = __builtin_amdgcn_mfma_f32_16x16x32_bf16(aX, bX[j], acc1[i][j], 0, 0, 0);
        acc2[i][j] = __builtin_amdgcn_mfma_f32_16x16x32_bf16(aH, bH[j], acc2[i][j], 0, 0, 0);
      }
    }
    __syncthreads();
  }

  const float invM = 1.0f / 1024.0f;
  const float invM2 = invM * invM;
  const float* gb = gate + b * C_N;
  const float* rxb = rx + b * C_N;
  const float* rbb = rb + b * C_N;
  for (int i = 0; i < 4; i++) {
    for (int r = 0; r < 4; r++) {
      int c = cblk + wr + i * 16 + (lane >> 4) * 4 + r;
      float gc = gb[c], rxc = rxb[c], rbc = rbb[c];
      for (int j = 0; j < 4; j++) {
        int d = dblk + wc + j * 16 + (lane & 15);
        float v = gc * gb[d] * (acc1[i][j][r] * invM - rxc * rxb[d] * invM2)
                + (acc2[i][j][r] * invM - rbc * rbb[d] * invM2);
        if (c == d) v += 1e-8f;
        size_t o = ((size_t)b * C_N + c) * C_N + d;
        if (f) ((unsigned short*)out)[o] = f2b(v);
        else   ((float*)out)[o] = v;
      }
    }
  }
}

extern "C" void kernel_launch(void* const* d_in, const int* in_sizes, int n_in,
                              void* d_out, int out_size, void* d_ws, size_t ws_size,
                              hipStream_t stream) {
  const void* h_in = d_in[0];
  const void* conv_w = d_in[1];
  const void* conv_b = d_in[2];

  char* ws = (char*)d_ws;
  int* flag = (int*)ws;
  int* mode = (int*)(ws + 64);
  float* pesum = (float*)(ws + 1024);                       // 2 KB
  float* rx = (float*)(ws + 4096);                          // 128 KB
  float* rb = rx + B_N * C_N;                               // 128 KB
  float* gate = rb + B_N * C_N;                             // 128 KB
  unsigned short* pe = (unsigned short*)(ws + (512 << 10)); // 1 MB -> ends 1.5 MB

  int wsOK = (ws_size >= (size_t)(1536 << 10)) ? 1 : 0;     // proven present (r3)
  int wsP  = (ws_size >= (size_t)(2048 << 10)) ? 1 : 0;     // P in ws if it fits
  unsigned short* Pp = wsP ? (unsigned short*)(ws + (1536 << 10))
                           : (unsigned short*)d_out + (size_t)63 * C_N * C_N;

  k_detect<<<1, 256, 0, stream>>>((const unsigned short*)h_in, flag);
  k_mode<<<1, 64, 0, stream>>>(flag, wsOK, mode);
  k_pe<<<(C_N * M_N) / 256, 256, 0, stream>>>(pe);
  k_pesum<<<C_N / 4, 256, 0, stream>>>(pe, pesum);
  k_sums<<<(B_N * C_N) / 4, 256, 0, stream>>>(h_in, flag, pesum, rx, rb);
  k_gate<<<(B_N * C_N) / 256, 256, 0, stream>>>(conv_w, conv_b, flag, rx, gate);
  k_P<<<dim3(4, 4, 1), 256, 0, stream>>>(pe, Pp);

  const unsigned short* h16 = (const unsigned short*)h_in;
  unsigned short* o16 = (unsigned short*)d_out;
  if (wsP) {
    // all 64 batches, XCD-swizzled (1024 = 8 groups x 128)
    k_cov3<<<1024, 256, 0, stream>>>(h16, pe, Pp, mode, rx, rb, gate, o16, 0, 1);
  } else {
    // P lives in d_out batch-63 slot: batches 0..55 swizzled, 56..62 plain,
    // then 63 alone (its threads read P at exactly the address they overwrite)
    k_cov3<<<896, 256, 0, stream>>>(h16, pe, Pp, mode, rx, rb, gate, o16, 0, 1);
    k_cov3<<<dim3(4, 4, 7), 256, 0, stream>>>(h16, pe, Pp, mode, rx, rb, gate, o16, 56, 0);
    k_cov3<<<dim3(4, 4, 1), 256, 0, stream>>>(h16, pe, Pp, mode, rx, rb, gate, o16, 63, 0);
  }
  dim3 g(C_N / 128, C_N / 128, B_N);
  k_cov<<<g, 256, 0, stream>>>(h_in, pe, flag, mode, rx, rb, gate, d_out);
}